// Round 2
// baseline (409.225 us; speedup 1.0000x reference)
//
#include <hip/hip_runtime.h>

#define BATCH 8192

// ---------------------------------------------------------------------------
// Kernel 1: per-sample fused conv1+pool+conv2+pool+v-dot+attention tail.
// One block = one sample, 256 threads.
// ---------------------------------------------------------------------------
__global__ __launch_bounds__(256) void fused_fwd(
    const float* __restrict__ x,        // [B,1,28,28]
    const float* __restrict__ params,   // [B,4]
    const float* __restrict__ c1w,      // [8,1,3,3]
    const float* __restrict__ c1b,      // [8]
    const float* __restrict__ c2w,      // [16,8,3,3]
    const float* __restrict__ c2b,      // [16]
    const float* __restrict__ qkvw,     // [12,784]
    const float* __restrict__ qkvb,     // [12]
    const float* __restrict__ outw,     // [4,4]
    const float* __restrict__ outb,     // [4]
    float* __restrict__ pre,            // ws: [B,4] pre-BN
    float* __restrict__ partials)       // ws: [256][8] (sum[4], sumsq[4])
{
    __shared__ float xs[900];        // padded input [30][30]
    __shared__ float p1[8 * 256];    // padded pooled conv1 [8][16][16]
    __shared__ float p2[784];        // pooled conv2 [16][7][7] flat
    __shared__ float w1s[80];        // conv1 w(72) + b(8)
    __shared__ float w2s[16 * 72];   // conv2 w [16][8][9]
    __shared__ float c2bs[16];
    __shared__ float vred[4][4];

    const int tid = threadIdx.x;
    const int b = blockIdx.x;

    // ---- stage input (zero-padded) + weights + zero p1 ----
    for (int i = tid; i < 900; i += 256) {
        int h = i / 30, w = i - h * 30;
        float v = 0.f;
        if (h >= 1 && h <= 28 && w >= 1 && w <= 28)
            v = x[b * 784 + (h - 1) * 28 + (w - 1)];
        xs[i] = v;
    }
    for (int i = tid; i < 2048; i += 256) p1[i] = 0.f;
    if (tid < 72) w1s[tid] = c1w[tid];
    if (tid >= 72 && tid < 80) w1s[tid] = c1b[tid - 72];
    for (int i = tid; i < 1152; i += 256) w2s[i] = c2w[i];
    if (tid < 16) c2bs[tid] = c2b[tid];
    __syncthreads();

    // ---- conv1 (1->8) + relu + maxpool2 -> p1 interior [8][14][14] ----
    for (int it = tid; it < 1568; it += 256) {
        int c = it / 196;
        int r = it - c * 196;
        int ph = r / 14, pw = r - ph * 14;
        const float* wc = &w1s[c * 9];
        float bias = w1s[72 + c];
        float m = 0.f;  // max(relu(.)) == max(0, max(.))
        #pragma unroll
        for (int dh = 0; dh < 2; ++dh) {
            #pragma unroll
            for (int dw = 0; dw < 2; ++dw) {
                int h = 2 * ph + dh, w = 2 * pw + dw;
                const float* pr = &xs[h * 30 + w];
                float a = bias
                    + pr[0]  * wc[0] + pr[1]  * wc[1] + pr[2]  * wc[2]
                    + pr[30] * wc[3] + pr[31] * wc[4] + pr[32] * wc[5]
                    + pr[60] * wc[6] + pr[61] * wc[7] + pr[62] * wc[8];
                m = fmaxf(m, a);
            }
        }
        p1[c * 256 + (ph + 1) * 16 + (pw + 1)] = m;
    }
    __syncthreads();

    // ---- conv2 (8->16) + relu + maxpool2 -> p2 [16][7][7] ----
    for (int it = tid; it < 784; it += 256) {
        int c = it / 49;
        int r = it - c * 49;
        int ph = r / 7, pw = r - ph * 7;
        const float* wc = &w2s[c * 72];
        float bias = c2bs[c];
        float m = 0.f;
        #pragma unroll
        for (int dh = 0; dh < 2; ++dh) {
            #pragma unroll
            for (int dw = 0; dw < 2; ++dw) {
                int h = 2 * ph + dh, w = 2 * pw + dw;
                float a = bias;
                #pragma unroll
                for (int ic = 0; ic < 8; ++ic) {
                    const float* pr = &p1[ic * 256 + h * 16 + w];
                    const float* wr = &wc[ic * 9];
                    a += pr[0]  * wr[0] + pr[1]  * wr[1] + pr[2]  * wr[2]
                       + pr[16] * wr[3] + pr[17] * wr[4] + pr[18] * wr[5]
                       + pr[32] * wr[6] + pr[33] * wr[7] + pr[34] * wr[8];
                }
                m = fmaxf(m, a);
            }
        }
        p2[it] = m;
    }
    __syncthreads();

    // ---- v = p2 . qkv_w[8..11] (q,k provably unused) ----
    float v0 = 0.f, v1 = 0.f, v2 = 0.f, v3 = 0.f;
    for (int i = tid; i < 784; i += 256) {
        float f = p2[i];
        v0 += f * qkvw[8  * 784 + i];
        v1 += f * qkvw[9  * 784 + i];
        v2 += f * qkvw[10 * 784 + i];
        v3 += f * qkvw[11 * 784 + i];
    }
    #pragma unroll
    for (int off = 32; off > 0; off >>= 1) {
        v0 += __shfl_xor(v0, off);
        v1 += __shfl_xor(v1, off);
        v2 += __shfl_xor(v2, off);
        v3 += __shfl_xor(v3, off);
    }
    const int lane = tid & 63, wv = tid >> 6;
    if (lane == 0) {
        vred[wv][0] = v0; vred[wv][1] = v1; vred[wv][2] = v2; vred[wv][3] = v3;
    }
    __syncthreads();

    // ---- scalar tail on thread 0 ----
    if (tid == 0) {
        float vv[4];
        #pragma unroll
        for (int j = 0; j < 4; ++j)
            vv[j] = vred[0][j] + vred[1][j] + vred[2][j] + vred[3][j] + qkvb[8 + j];

        float lg[4];
        float run = 1.f;
        #pragma unroll
        for (int j = 0; j < 4; ++j) { run *= cosf(params[b * 4 + j]); lg[j] = run; }
        float mx = fmaxf(fmaxf(lg[0], lg[1]), fmaxf(lg[2], lg[3]));
        float e[4], s = 0.f;
        #pragma unroll
        for (int j = 0; j < 4; ++j) { e[j] = expf(lg[j] - mx); s += e[j]; }
        float inv = 1.f / s;
        float av[4];
        #pragma unroll
        for (int j = 0; j < 4; ++j) av[j] = e[j] * inv * vv[j];

        #pragma unroll
        for (int o = 0; o < 4; ++o) {
            float t = outb[o];
            #pragma unroll
            for (int j = 0; j < 4; ++j) t += outw[o * 4 + j] * av[j];
            pre[b * 4 + o] = t;
            atomicAdd(&partials[(b & 255) * 8 + o], t);
            atomicAdd(&partials[(b & 255) * 8 + 4 + o], t * t);
        }
    }
}

// ---------------------------------------------------------------------------
// Kernel 2: reduce 256 partial slots -> mu[4], inv_std[4]
// ---------------------------------------------------------------------------
__global__ __launch_bounds__(256) void bn_stats(
    const float* __restrict__ partials, float* __restrict__ stats)
{
    __shared__ float red[8][32];
    const int tid = threadIdx.x;
    const int val = tid & 7, grp = tid >> 3;
    float s = 0.f;
    for (int slot = grp; slot < 256; slot += 32) s += partials[slot * 8 + val];
    red[val][grp] = s;
    __syncthreads();
    if (tid < 8) {
        float t = 0.f;
        #pragma unroll
        for (int g = 0; g < 32; ++g) t += red[tid][g];
        red[tid][0] = t;
    }
    __syncthreads();
    if (tid < 4) {
        float mu  = red[tid][0] * (1.f / 8192.f);
        float var = red[tid + 4][0] * (1.f / 8192.f) - mu * mu;
        stats[tid]     = mu;
        stats[4 + tid] = rsqrtf(var + 1e-5f);
    }
}

// ---------------------------------------------------------------------------
// Kernel 3: apply BN
// ---------------------------------------------------------------------------
__global__ __launch_bounds__(256) void bn_apply(
    const float* __restrict__ pre, const float* __restrict__ stats,
    const float* __restrict__ gamma, const float* __restrict__ beta,
    float* __restrict__ out)
{
    const int i = blockIdx.x * 256 + threadIdx.x;
    const int c = i & 3;
    out[i] = (pre[i] - stats[c]) * stats[4 + c] * gamma[c] + beta[c];
}

extern "C" void kernel_launch(void* const* d_in, const int* in_sizes, int n_in,
                              void* d_out, int out_size, void* d_ws, size_t ws_size,
                              hipStream_t stream) {
    const float* x      = (const float*)d_in[0];
    const float* params = (const float*)d_in[1];
    const float* c1w    = (const float*)d_in[2];
    const float* c1b    = (const float*)d_in[3];
    const float* c2w    = (const float*)d_in[4];
    const float* c2b    = (const float*)d_in[5];
    const float* qkvw   = (const float*)d_in[6];
    const float* qkvb   = (const float*)d_in[7];
    const float* outw   = (const float*)d_in[8];
    const float* outb   = (const float*)d_in[9];
    const float* gamma  = (const float*)d_in[10];
    const float* beta   = (const float*)d_in[11];

    float* ws       = (float*)d_ws;
    float* pre      = ws;                    // 32768 floats
    float* partials = ws + 32768;            // 2048 floats
    float* stats    = ws + 32768 + 2048;     // 8 floats

    hipMemsetAsync(partials, 0, 2048 * sizeof(float), stream);
    fused_fwd<<<BATCH, 256, 0, stream>>>(x, params, c1w, c1b, c2w, c2b,
                                         qkvw, qkvb, outw, outb, pre, partials);
    bn_stats<<<1, 256, 0, stream>>>(partials, stats);
    bn_apply<<<32768 / 256, 256, 0, stream>>>(pre, stats, gamma, beta,
                                              (float*)d_out);
}